// Round 11
// baseline (405.248 us; speedup 1.0000x reference)
//
#include <hip/hip_runtime.h>
#include <math.h>

#define BN_SF 0.9999950000374997f  /* 1/sqrt(1+1e-5) */

typedef __attribute__((ext_vector_type(8))) short short8v;
typedef __attribute__((ext_vector_type(4))) float float4v;

__device__ __forceinline__ float sigm(float x) { return 1.0f / (1.0f + expf(-x)); }

__device__ __forceinline__ short f2bf(float x) {
    unsigned u = __builtin_bit_cast(unsigned, x);
    unsigned r = (u + 0x7fffu + ((u >> 16) & 1u)) >> 16;
    return (short)r;
}
__device__ __forceinline__ float bf2f(short h) {
    unsigned u = ((unsigned)(unsigned short)h) << 16;
    return __builtin_bit_cast(float, u);
}

// dst-linear B-fragment converter: group g writes dst[8g..8g+7].
template <int K, int N>
__device__ __forceinline__ void cvtB8(const float* __restrict__ src, short* __restrict__ dst,
                                      float scale, int g) {
    const int KCN = K >> 5;
    int ntg = g / (KCN * 64);
    int rem = g - ntg * (KCN * 64);
    int kc = rem >> 6, lane = rem & 63;
    int n = ntg * 16 + (lane & 15);
    int k0 = kc * 32 + ((lane >> 4) << 3);
    short8v v;
#pragma unroll
    for (int j = 0; j < 8; ++j) v[j] = f2bf(scale * src[(size_t)(k0 + j) * N + n]);
    *(short8v*)(dst + (size_t)g * 8) = v;
}

struct SetupP {
    const float *Wm2, *Wd1, *Wd2, *Wm1, *Wih, *Whh, *Wpat, *bpat, *bm1, *c0;
    short *Wm2s, *Wd1f, *Wd2f, *Wm1f, *WgHi, *WgLo;
    float *uv, *cbuf;
};

// flattened, balanced: every thread handles <=1 group of each space
__global__ __launch_bounds__(256) void k_setup(SetupP p) {
    int gt = blockIdx.x * 256 + threadIdx.x;
    int stride = gridDim.x * 256;
    // flat fragment-group space: Wm2 65536 | Wd1 147456 | Wd2 16384 | Wm1 8192 | Wg 12288
    for (int g = gt; g < 249856; g += stride) {
        if (g < 65536) cvtB8<512, 1024>(p.Wm2, p.Wm2s, 1.f, g);
        else if (g < 212992) cvtB8<1152, 1024>(p.Wd1, p.Wd1f, 1.f, g - 65536);
        else if (g < 229376) cvtB8<1024, 128>(p.Wd2, p.Wd2f, 1.f, g - 212992);
        else if (g < 237568) cvtB8<128, 512>(p.Wm1, p.Wm1f, 0.05f, g - 229376);
        else {
            int gg = g - 237568;
            int ntg = gg / (6 * 64);
            int rem = gg - ntg * (6 * 64);
            int kc = rem >> 6, lane = rem & 63;
            int n = ntg * 16 + (lane & 15);
            int k0 = kc * 32 + ((lane >> 4) << 3);
            short8v vh, vl;
#pragma unroll
            for (int j = 0; j < 8; ++j) {
                int k = k0 + j;
                float v = (k < 64) ? p.Wih[(size_t)k * 512 + n] : p.Whh[(size_t)(k - 64) * 512 + n];
                short hi = f2bf(v);
                vh[j] = hi; vl[j] = f2bf(v - bf2f(hi));
            }
            *(short8v*)(p.WgHi + (size_t)gg * 8) = vh;
            *(short8v*)(p.WgLo + (size_t)gg * 8) = vl;
        }
    }
    for (int i = gt; i < 32768; i += stride)   // cbuf copy as float4
        ((float4*)p.cbuf)[i] = ((const float4*)p.c0)[i];
    if (blockIdx.x == 0) {  // uv: rank-1 agent-type folding
        __shared__ float rw[64];
        int t = threadIdx.x;
        if (t < 64) { float s = 0.f; for (int k = 0; k < 6; ++k) s += p.Wpat[k * 64 + t]; rw[t] = s; }
        __syncthreads();
        for (int c = t; c < 512; c += 256) {
            float u = 0.f, v = 0.f;
            for (int e = 0; e < 64; ++e) {
                float wg = p.Wm1[(128 + e) * 512 + c];
                u += rw[e] * wg; v += p.bpat[e] * wg;
            }
            p.uv[c] = 0.05f * u; p.uv[512 + c] = 0.05f * v + p.bm1[c];
        }
    }
}

// ---- per step: dh1(read hwf+phwp) -> dh2 -> LSTM(gdi + h-part MFMA) -> rel/di-frag/m1 ----
// grid 64 x 512 (8 waves); block b: scene s=b>>1, half mt=b&1
__global__ __launch_bounds__(512, 4) void k_step(
    const short* __restrict__ WgHi, const short* __restrict__ WgLo,
    const short* __restrict__ Wm1f, const short* __restrict__ Wd2f,
    const float* __restrict__ Wih,
    const float* __restrict__ Whp, const float* __restrict__ bhp,
    const float* __restrict__ Wsp, const float* __restrict__ bsp,
    const float* __restrict__ bih, const float* __restrict__ bhh,
    const float* __restrict__ bd1, const float* __restrict__ bd2,
    const float* __restrict__ at0, const float* __restrict__ uv,
    const float* __restrict__ h0, const float* __restrict__ lpr,
    const float* __restrict__ phwp, const short* __restrict__ hwf,
    const float* __restrict__ gdip, int first,
    float* __restrict__ cbuf, short* __restrict__ hf_out,
    short* __restrict__ difh, short* __restrict__ difl,
    short* __restrict__ m1s, float* __restrict__ outrel) {
    __shared__ float sgu[16 * 512];      // 32KB union: dh1L (shorts) / sg (f32)
    __shared__ float sh[16][128];
    __shared__ float phws[1024];
    __shared__ short xfh[4 * 512];
    __shared__ short xfl[4 * 512];
    __shared__ short xm[4 * 512];
    __shared__ float sdi0[16][64];
    __shared__ float sat[16];
    __shared__ float srel[16][2];
    short* dh1L = (short*)sgu;
    float* sg = sgu;

    int t = threadIdx.x, b = blockIdx.x;
    int l = t & 63, w = t >> 6;
    int s = b >> 1, mt = b & 1, r0 = b * 16;
    int rbase = (l >> 4) << 2;

    if (t < 16) sat[t] = at0[r0 + t];

    if (first) {
        for (int i = t; i < 16 * 128; i += 512) sh[i >> 7][i & 127] = h0[r0 * 128 + i];
        for (int i = t; i < 16 * 64; i += 512) {
            int row = i >> 6, k = i & 63;
            sdi0[row][k] = lpr[(r0 + row) * 2] * Wsp[k] + lpr[(r0 + row) * 2 + 1] * Wsp[64 + k] + bsp[k];
        }
        __syncthreads();
    } else {
        // phws = bd1 + sum of 8 phw partials
        for (int i = t; i < 1024; i += 512) {
            float v = bd1[i];
#pragma unroll
            for (int ct = 0; ct < 8; ++ct) v += phwp[(size_t)s * 8192 + ct * 1024 + i];
            phws[i] = v;
        }
        __syncthreads();
        // dh1L = bnrelu(hwf + phws) in A-frag layout (no MFMA)
        for (int g = t; g < 2048; g += 512) {
            int kc = g >> 6, ll = g & 63;
            int colbase = kc * 32 + ((ll >> 4) << 3);
            short8v hv = *(const short8v*)(hwf + (size_t)b * 16384 + g * 8);
            short8v o;
#pragma unroll
            for (int j = 0; j < 8; ++j)
                o[j] = f2bf(fmaxf(BN_SF * (bf2f(hv[j]) + phws[colbase + j]), 0.f));
            *(short8v*)(dh1L + g * 8) = o;
        }
        __syncthreads();
        // dh2 (K=1024) batched
        float4v hacc = {0.f, 0.f, 0.f, 0.f};
        const short* ap = dh1L + l * 8;
        const short* bp = Wd2f + (size_t)w * 16384 + l * 8;
#pragma unroll 1
        for (int kt = 0; kt < 4; ++kt) {
            short8v B[8], A[8];
#pragma unroll
            for (int kk = 0; kk < 8; ++kk) B[kk] = *(const short8v*)(bp + (kt * 8 + kk) * 512);
#pragma unroll
            for (int kk = 0; kk < 8; ++kk) A[kk] = *(const short8v*)(ap + (kt * 8 + kk) * 512);
#pragma unroll
            for (int kk = 0; kk < 8; ++kk)
                hacc = __builtin_amdgcn_mfma_f32_16x16x32_bf16(A[kk], B[kk], hacc, 0, 0, 0);
        }
        int col = w * 16 + (l & 15);
        float bb2 = bd2[col];
        __syncthreads();
#pragma unroll
        for (int r = 0; r < 4; ++r)
            sh[rbase + r][col] = fmaxf(BN_SF * (hacc[r] + bb2), 0.f);
        __syncthreads();
    }

    // xf: h-only hi/lo A-frags (4 kc)
    for (int i = t; i < 4 * 512; i += 512) {
        int pos = i & 511, kc = i >> 9;
        int ll = pos >> 3, j = pos & 7;
        int row = ll & 15, kh = kc * 32 + ((ll >> 4) << 3) + j;
        float v = sh[row][kh];
        short hi = f2bf(v);
        xfh[i] = hi;
        xfl[i] = f2bf(v - bf2f(hi));
    }
    __syncthreads();

    // gates: init from gdi (or inline f32 di-part at step 0), + h-part MFMA (4 kc)
    {
        float4v ga[4];
#pragma unroll
        for (int q = 0; q < 4; ++q) {
            int col = (w * 4 + q) * 16 + (l & 15);
            if (first) {
                float a0 = bih[col] + bhh[col];
                float acc[4] = {a0, a0, a0, a0};
                for (int k = 0; k < 64; ++k) {
                    float wv = Wih[(size_t)k * 512 + col];
#pragma unroll
                    for (int r = 0; r < 4; ++r) acc[r] += sdi0[rbase + r][k] * wv;
                }
#pragma unroll
                for (int r = 0; r < 4; ++r) ga[q][r] = acc[r];
            } else {
#pragma unroll
                for (int r = 0; r < 4; ++r)
                    ga[q][r] = gdip[(size_t)((s * 2 + mt) * 16 + rbase + r) * 512 + col];
            }
        }
#pragma unroll 1
        for (int kt = 0; kt < 2; ++kt) {
            short8v BH[2][4], BL[2][4], AH[2], AL[2];
#pragma unroll
            for (int kk = 0; kk < 2; ++kk) {
                int kcx = kt * 2 + kk;
#pragma unroll
                for (int q = 0; q < 4; ++q) {
                    int nf = w * 4 + q;
                    BH[kk][q] = *(const short8v*)(WgHi + (size_t)nf * 3072 + (2 + kcx) * 512 + l * 8);
                    BL[kk][q] = *(const short8v*)(WgLo + (size_t)nf * 3072 + (2 + kcx) * 512 + l * 8);
                }
                AH[kk] = *(const short8v*)(&xfh[kcx * 512 + l * 8]);
                AL[kk] = *(const short8v*)(&xfl[kcx * 512 + l * 8]);
            }
#pragma unroll
            for (int kk = 0; kk < 2; ++kk)
#pragma unroll
                for (int q = 0; q < 4; ++q) {
                    ga[q] = __builtin_amdgcn_mfma_f32_16x16x32_bf16(AH[kk], BH[kk][q], ga[q], 0, 0, 0);
                    ga[q] = __builtin_amdgcn_mfma_f32_16x16x32_bf16(AH[kk], BL[kk][q], ga[q], 0, 0, 0);
                    ga[q] = __builtin_amdgcn_mfma_f32_16x16x32_bf16(AL[kk], BH[kk][q], ga[q], 0, 0, 0);
                }
        }
#pragma unroll
        for (int q = 0; q < 4; ++q) {
            int col = (w * 4 + q) * 16 + (l & 15);
#pragma unroll
            for (int r = 0; r < 4; ++r)
                sg[(rbase + r) * 512 + col] = ga[q][r];
        }
    }
    __syncthreads();

    // LSTM pointwise -> sh (new h)
    for (int i = t; i < 16 * 128; i += 512) {
        int row = i >> 7, j = i & 127;
        float gi = sg[row * 512 + j], gf = sg[row * 512 + j + 128];
        float gg = sg[row * 512 + j + 256], go = sg[row * 512 + j + 384];
        float cn = sigm(gf) * cbuf[(r0 + row) * 128 + j] + sigm(gi) * tanhf(gg);
        float hn = sigm(go) * tanhf(cn);
        cbuf[(r0 + row) * 128 + j] = cn;
        sh[row][j] = hn;
    }
    __syncthreads();

    // rel (f32, exact -> output)
    if (t < 32) {
        int row = t >> 1, d = t & 1;
        float s2 = bhp[d];
        for (int k = 0; k < 128; ++k) s2 += sh[row][k] * Whp[k * 2 + d];
        srel[row][d] = s2;
        outrel[(r0 + row) * 2 + d] = s2;
    }
    // new-h A-frags (LDS xm + global hf)
    for (int i = t; i < 4 * 512; i += 512) {
        int pos = i & 511, kc = i >> 9;
        int ll = pos >> 3, j = pos & 7;
        int row = ll & 15, k = kc * 32 + ((ll >> 4) << 3) + j;
        short hv = f2bf(sh[row][k]);
        xm[i] = hv;
        hf_out[(size_t)b * 2048 + i] = hv;
    }
    __syncthreads();

    // di(t+1) hi/lo frags (kc 0..1)
    for (int i = t; i < 1024; i += 512) {
        int pos = i & 511, kc = i >> 9;
        int ll = pos >> 3, j = pos & 7;
        int row = ll & 15, k = kc * 32 + ((ll >> 4) << 3) + j;
        float dv = srel[row][0] * Wsp[k] + srel[row][1] * Wsp[64 + k] + bsp[k];
        short hi = f2bf(dv);
        difh[(size_t)b * 1024 + i] = hi;
        difl[(size_t)b * 1024 + i] = f2bf(dv - bf2f(hi));
    }

    // m1 MFMA -> m1s
    {
        float4v ma[4] = {{0,0,0,0},{0,0,0,0},{0,0,0,0},{0,0,0,0}};
        short8v A[4], B[4][4];
#pragma unroll
        for (int kc = 0; kc < 4; ++kc) {
#pragma unroll
            for (int q = 0; q < 4; ++q)
                B[kc][q] = *(const short8v*)(Wm1f + (size_t)(w * 4 + q) * 2048 + kc * 512 + l * 8);
            A[kc] = *(const short8v*)(&xm[kc * 512 + l * 8]);
        }
#pragma unroll
        for (int kc = 0; kc < 4; ++kc)
#pragma unroll
            for (int q = 0; q < 4; ++q)
                ma[q] = __builtin_amdgcn_mfma_f32_16x16x32_bf16(A[kc], B[kc][q], ma[q], 0, 0, 0);
#pragma unroll
        for (int q = 0; q < 4; ++q) {
            int col = (w * 4 + q) * 16 + (l & 15);
            float uc = uv[col], vc = uv[512 + col];
#pragma unroll
            for (int r = 0; r < 4; ++r) {
                int rowC = rbase + r;
                float m1v = fmaxf(BN_SF * (ma[q][r] + sat[rowC] * uc + vc), 0.f);
                int kcD = col >> 5;
                int laneD = rowC + (((col & 31) >> 3) << 4);
                m1s[(size_t)s * 16384 + kcD * 1024 + mt * 512 + laneD * 8 + (col & 7)] = f2bf(m1v);
            }
        }
    }
}

// ---- per step: m2+colmax -> phw partial; hw = h@Wd1h (n-slice); gdi = di@Wg_di (n-slice) ----
// grid 256 = 32 scenes x 8 slices; 512 thr = 8 waves
__global__ __launch_bounds__(512, 4) void k_m2(
    const short* __restrict__ m1s, const short* __restrict__ Wm2s,
    const short* __restrict__ Wd1f,
    const short* __restrict__ WgHi, const short* __restrict__ WgLo,
    const float* __restrict__ bm2, const float* __restrict__ bih, const float* __restrict__ bhh,
    const short* __restrict__ hf, const short* __restrict__ difh, const short* __restrict__ difl,
    float* __restrict__ phwp, short* __restrict__ hwf, float* __restrict__ gdip) {
    __shared__ short sphb[128];
    int t = threadIdx.x, l = t & 63, w = t >> 6;
    int s = blockIdx.x >> 3, ct = blockIdx.x & 7;
    int rbase = (l >> 4) << 2;

    // m2: wave w -> nf = ct*8+w, both m-halves
    {
        int nf = ct * 8 + w;
        const short* ap = m1s + (size_t)s * 16384 + l * 8;
        const short* bp = Wm2s + (size_t)nf * 8192 + l * 8;
        float4v acc0 = {0,0,0,0}, acc1 = {0,0,0,0};
#pragma unroll 1
        for (int kt = 0; kt < 4; ++kt) {
            short8v A0[4], A1[4], B[4];
#pragma unroll
            for (int kk = 0; kk < 4; ++kk) {
                int kc = kt * 4 + kk;
                B[kk] = *(const short8v*)(bp + kc * 512);
                A0[kk] = *(const short8v*)(ap + kc * 1024);
                A1[kk] = *(const short8v*)(ap + kc * 1024 + 512);
            }
#pragma unroll
            for (int kk = 0; kk < 4; ++kk) {
                acc0 = __builtin_amdgcn_mfma_f32_16x16x32_bf16(A0[kk], B[kk], acc0, 0, 0, 0);
                acc1 = __builtin_amdgcn_mfma_f32_16x16x32_bf16(A1[kk], B[kk], acc1, 0, 0, 0);
            }
        }
        float m = acc0[0];
#pragma unroll
        for (int ri = 1; ri < 4; ++ri) m = fmaxf(m, acc0[ri]);
#pragma unroll
        for (int ri = 0; ri < 4; ++ri) m = fmaxf(m, acc1[ri]);
        m = fmaxf(m, __shfl_xor(m, 16, 64));
        m = fmaxf(m, __shfl_xor(m, 32, 64));
        if (l < 16) {
            int col = nf * 16 + l;
            sphb[w * 16 + l] = f2bf(fmaxf(BN_SF * (m + bm2[col]), 0.f));
        }
    }

    // hw = h @ Wd1h for n-slice (nf = ct*8+w), both halves -> hwf A-frag layout (bf16)
    {
        int nf = ct * 8 + w;
        short8v Bh[4];
#pragma unroll
        for (int kc = 0; kc < 4; ++kc)
            Bh[kc] = *(const short8v*)(Wd1f + (size_t)nf * 18432 + kc * 512 + l * 8);
        int col = nf * 16 + (l & 15);
        int kcD = col >> 5, jD = col & 7, lD = ((col & 31) >> 3) << 4;
#pragma unroll
        for (int m2i = 0; m2i < 2; ++m2i) {
            short8v Ah[4];
#pragma unroll
            for (int kc = 0; kc < 4; ++kc)
                Ah[kc] = *(const short8v*)(hf + (size_t)(s * 2 + m2i) * 2048 + kc * 512 + l * 8);
            float4v hacc = {0.f, 0.f, 0.f, 0.f};
#pragma unroll
            for (int kc = 0; kc < 4; ++kc)
                hacc = __builtin_amdgcn_mfma_f32_16x16x32_bf16(Ah[kc], Bh[kc], hacc, 0, 0, 0);
#pragma unroll
            for (int r = 0; r < 4; ++r)
                hwf[(size_t)(s * 2 + m2i) * 16384 + kcD * 512 + (rbase + r + lD) * 8 + jD] = f2bf(hacc[r]);
        }
    }

    // gdi = di @ Wg[kc0..1] + biases, n-slice: wave (mt=w>>2, q=w&3) -> gate-nf = ct*4+q
    {
        int m2i = w >> 2, q = w & 3;
        int nfg = ct * 4 + q;
        float4v g = {0.f, 0.f, 0.f, 0.f};
#pragma unroll
        for (int kc = 0; kc < 2; ++kc) {
            short8v AH = *(const short8v*)(difh + (size_t)(s * 2 + m2i) * 1024 + kc * 512 + l * 8);
            short8v AL = *(const short8v*)(difl + (size_t)(s * 2 + m2i) * 1024 + kc * 512 + l * 8);
            short8v BH = *(const short8v*)(WgHi + (size_t)nfg * 3072 + kc * 512 + l * 8);
            short8v BL = *(const short8v*)(WgLo + (size_t)nfg * 3072 + kc * 512 + l * 8);
            g = __builtin_amdgcn_mfma_f32_16x16x32_bf16(AH, BH, g, 0, 0, 0);
            g = __builtin_amdgcn_mfma_f32_16x16x32_bf16(AH, BL, g, 0, 0, 0);
            g = __builtin_amdgcn_mfma_f32_16x16x32_bf16(AL, BH, g, 0, 0, 0);
        }
        int col = nfg * 16 + (l & 15);
        float bb = bih[col] + bhh[col];
#pragma unroll
        for (int r = 0; r < 4; ++r)
            gdip[(size_t)((s * 2 + m2i) * 16 + rbase + r) * 512 + col] = g[r] + bb;
    }
    __syncthreads();

    // phw partial: ph-slice(128) @ Wd1p[4+ct*4 kc, all 1024 cols], broadcast-A
    {
        short8v Ap[4];
#pragma unroll
        for (int kk = 0; kk < 4; ++kk)
            Ap[kk] = *(const short8v*)(sphb + kk * 32 + ((l >> 4) << 3));
#pragma unroll 1
        for (int q2 = 0; q2 < 4; ++q2) {
            short8v B[2][4];
#pragma unroll
            for (int qq = 0; qq < 2; ++qq)
#pragma unroll
                for (int kk = 0; kk < 4; ++kk)
                    B[qq][kk] = *(const short8v*)(Wd1f + (size_t)(w * 8 + q2 * 2 + qq) * 18432
                                                  + (size_t)(4 + ct * 4 + kk) * 512 + l * 8);
            float4v acc2[2] = {{0,0,0,0},{0,0,0,0}};
#pragma unroll
            for (int kk = 0; kk < 4; ++kk)
#pragma unroll
                for (int qq = 0; qq < 2; ++qq)
                    acc2[qq] = __builtin_amdgcn_mfma_f32_16x16x32_bf16(Ap[kk], B[qq][kk], acc2[qq], 0, 0, 0);
            if (l < 16) {
#pragma unroll
                for (int qq = 0; qq < 2; ++qq) {
                    int nf_p = w * 8 + q2 * 2 + qq;
                    phwp[(size_t)s * 8192 + ct * 1024 + nf_p * 16 + l] = acc2[qq][0];
                }
            }
        }
    }
}

// ---- final: dh1 from hwf+phwp, dh2 -> out h ----
__global__ __launch_bounds__(512, 4) void k_hfin(const short* __restrict__ Wd2f,
                                                 const float* __restrict__ bd1,
                                                 const float* __restrict__ bd2,
                                                 const float* __restrict__ phwp,
                                                 const short* __restrict__ hwf,
                                                 float* __restrict__ outh) {
    __shared__ float phws[1024];
    __shared__ short dh1L[16384];
    int t = threadIdx.x, b = blockIdx.x;
    int l = t & 63, w = t >> 6;
    int s = b >> 1, rbase = (l >> 4) << 2;

    for (int i = t; i < 1024; i += 512) {
        float v = bd1[i];
#pragma unroll
        for (int ct = 0; ct < 8; ++ct) v += phwp[(size_t)s * 8192 + ct * 1024 + i];
        phws[i] = v;
    }
    __syncthreads();
    for (int g = t; g < 2048; g += 512) {
        int kc = g >> 6, ll = g & 63;
        int colbase = kc * 32 + ((ll >> 4) << 3);
        short8v hv = *(const short8v*)(hwf + (size_t)b * 16384 + g * 8);
        short8v o;
#pragma unroll
        for (int j = 0; j < 8; ++j)
            o[j] = f2bf(fmaxf(BN_SF * (bf2f(hv[j]) + phws[colbase + j]), 0.f));
        *(short8v*)(dh1L + g * 8) = o;
    }
    __syncthreads();
    float4v hacc = {0.f, 0.f, 0.f, 0.f};
    const short* ap = dh1L + l * 8;
    const short* bp = Wd2f + (size_t)w * 16384 + l * 8;
#pragma unroll 1
    for (int kt = 0; kt < 4; ++kt) {
        short8v B[8], A[8];
#pragma unroll
        for (int kk = 0; kk < 8; ++kk) B[kk] = *(const short8v*)(bp + (kt * 8 + kk) * 512);
#pragma unroll
        for (int kk = 0; kk < 8; ++kk) A[kk] = *(const short8v*)(ap + (kt * 8 + kk) * 512);
#pragma unroll
        for (int kk = 0; kk < 8; ++kk)
            hacc = __builtin_amdgcn_mfma_f32_16x16x32_bf16(A[kk], B[kk], hacc, 0, 0, 0);
    }
    int col = w * 16 + (l & 15);
    float bb2 = bd2[col];
#pragma unroll
    for (int r = 0; r < 4; ++r)
        outh[(b * 16 + rbase + r) * 128 + col] = fmaxf(BN_SF * (hacc[r] + bb2), 0.f);
}

extern "C" void kernel_launch(void* const* d_in, const int* in_sizes, int n_in,
                              void* d_out, int out_size, void* d_ws, size_t ws_size,
                              hipStream_t stream) {
    const float* lpr   = (const float*)d_in[1];
    const float* h0    = (const float*)d_in[2];
    const float* c0    = (const float*)d_in[3];
    const float* at0   = (const float*)d_in[6];
    const float* W_sp  = (const float*)d_in[8];
    const float* b_sp  = (const float*)d_in[9];
    const float* W_ih  = (const float*)d_in[10];
    const float* W_hh  = (const float*)d_in[11];
    const float* b_ih  = (const float*)d_in[12];
    const float* b_hh  = (const float*)d_in[13];
    const float* W_h2p = (const float*)d_in[14];
    const float* b_h2p = (const float*)d_in[15];
    const float* Wp_at = (const float*)d_in[20];
    const float* bp_at = (const float*)d_in[21];
    const float* Wm1   = (const float*)d_in[26];
    const float* bm1   = (const float*)d_in[27];
    const float* Wm2   = (const float*)d_in[28];
    const float* bm2   = (const float*)d_in[29];
    const float* Wd1   = (const float*)d_in[30];
    const float* bd1   = (const float*)d_in[31];
    const float* Wd2   = (const float*)d_in[32];
    const float* bd2   = (const float*)d_in[33];
    float* out = (float*)d_out;

    float* ws    = (float*)d_ws;
    float* uv    = ws;                     // 1024 f
    float* cbuf  = uv + 1024;              // 131072 f
    float* phwp  = cbuf + 131072;          // 262144 f
    float* gdip  = phwp + 262144;          // 524288 f
    short* hf    = (short*)(gdip + 524288);  // 131072 sh
    short* difh  = hf + 131072;            // 65536 sh
    short* difl  = difh + 65536;           // 65536 sh
    short* m1s   = difl + 65536;           // 524288 sh
    short* hwf   = m1s + 524288;           // 1048576 sh
    short* Wm2s  = hwf + 1048576;          // 524288 sh
    short* Wd1f  = Wm2s + 524288;          // 1179648 sh
    short* Wd2f  = Wd1f + 1179648;         // 131072 sh
    short* Wm1f  = Wd2f + 131072;          // 65536 sh
    short* WgHi  = Wm1f + 65536;           // 98304 sh
    short* WgLo  = WgHi + 98304;           // 98304 sh

    SetupP sp;
    sp.Wm2 = Wm2; sp.Wd1 = Wd1; sp.Wd2 = Wd2; sp.Wm1 = Wm1;
    sp.Wih = W_ih; sp.Whh = W_hh; sp.Wpat = Wp_at; sp.bpat = bp_at; sp.bm1 = bm1;
    sp.c0 = c0;
    sp.Wm2s = Wm2s; sp.Wd1f = Wd1f; sp.Wd2f = Wd2f;
    sp.Wm1f = Wm1f; sp.WgHi = WgHi; sp.WgLo = WgLo;
    sp.uv = uv; sp.cbuf = cbuf;

    k_setup<<<1024, 256, 0, stream>>>(sp);

    for (int t = 0; t < 12; ++t) {
        k_step<<<64, 512, 0, stream>>>(WgHi, WgLo, Wm1f, Wd2f, W_ih,
                                       W_h2p, b_h2p, W_sp, b_sp, b_ih, b_hh,
                                       bd1, bd2, at0, uv, h0, lpr,
                                       phwp, hwf, gdip, (t == 0) ? 1 : 0,
                                       cbuf, hf, difh, difl, m1s,
                                       out + (size_t)t * 2048);
        k_m2<<<256, 512, 0, stream>>>(m1s, Wm2s, Wd1f, WgHi, WgLo,
                                      bm2, b_ih, b_hh, hf, difh, difl,
                                      phwp, hwf, gdip);
    }
    k_hfin<<<64, 512, 0, stream>>>(Wd2f, bd1, bd2, phwp, hwf, out + 24576);
}

// Round 12
// 327.767 us; speedup vs baseline: 1.2364x; 1.2364x over previous
//
#include <hip/hip_runtime.h>
#include <math.h>

#define BN_SF 0.9999950000374997f  /* 1/sqrt(1+1e-5) */

typedef __attribute__((ext_vector_type(8))) short short8v;
typedef __attribute__((ext_vector_type(4))) float float4v;

__device__ __forceinline__ float sigm(float x) { return 1.0f / (1.0f + expf(-x)); }

__device__ __forceinline__ short f2bf(float x) {
    unsigned u = __builtin_bit_cast(unsigned, x);
    unsigned r = (u + 0x7fffu + ((u >> 16) & 1u)) >> 16;
    return (short)r;
}
__device__ __forceinline__ float bf2f(short h) {
    unsigned u = ((unsigned)(unsigned short)h) << 16;
    return __builtin_bit_cast(float, u);
}

struct SetupP {
    const float *Wm2, *Wd1, *Wd2, *Wm1, *Wih, *Whh, *Wpat, *bpat, *bm1, *c0;
    const float *Wsp, *bsp, *bih, *bhh;
    short *Wm2s, *Wd1f, *Wd2f, *Wm1f, *WghHi, *WghLo;
    float *uv, *cbuf, *fc;
};

// LDS-staged tile converter: tile = 32k x 64n, coalesced src reads + coalesced frag writes.
// tile table: [0,256) Wm2(512,1024) | [256,832) Wd1(1152,1024) | [832,896) Wd2(1024,128)
//             [896,928) Wm1(128,512) scale .05 | [928,960) Wgh(128,512) hi/lo from Whh
__global__ __launch_bounds__(256) void k_setup(SetupP p) {
    __shared__ float tile[32][65];
    __shared__ float rw2[64], su[4][64], sv[4][64];
    int b = blockIdx.x, t = threadIdx.x;

    if (b < 960) {
        const float* src; short* dst; short* dst2 = nullptr;
        int K, N, tm; float scale = 1.f;
        if (b < 256)      { src = p.Wm2; dst = p.Wm2s; K = 512;  N = 1024; tm = b; }
        else if (b < 832) { src = p.Wd1; dst = p.Wd1f; K = 1152; N = 1024; tm = b - 256; }
        else if (b < 896) { src = p.Wd2; dst = p.Wd2f; K = 1024; N = 128;  tm = b - 832; }
        else if (b < 928) { src = p.Wm1; dst = p.Wm1f; K = 128;  N = 512;  tm = b - 896; scale = 0.05f; }
        else              { src = p.Whh; dst = p.WghHi; dst2 = p.WghLo; K = 128; N = 512; tm = b - 928; }
        int tiles_n = N >> 6;
        int kt = tm / tiles_n, nt = tm - kt * tiles_n;
        for (int i = t; i < 2048; i += 256) {
            int r = i >> 6, c = i & 63;
            tile[r][c] = scale * src[(size_t)(kt * 32 + r) * N + nt * 64 + c];
        }
        __syncthreads();
        int lane = t & 63, ntgl = t >> 6;
        int ntg = nt * 4 + ntgl;
        size_t off = (size_t)ntg * ((K >> 5) * 512) + (size_t)kt * 512 + lane * 8;
        int kl = (lane >> 4) << 3, nl = ntgl * 16 + (lane & 15);
        short8v vh, vl;
#pragma unroll
        for (int j = 0; j < 8; ++j) {
            float v = tile[kl + j][nl];
            short hi = f2bf(v);
            vh[j] = hi; vl[j] = f2bf(v - bf2f(hi));
        }
        *(short8v*)(dst + off) = vh;
        if (dst2) *(short8v*)(dst2 + off) = vl;
    } else {
        // cbuf copy (blocks 960..1023): 32768 float4 over 64 blocks
        int i0 = (b - 960) * 256 + t;
        ((float4*)p.cbuf)[i0] = ((const float4*)p.c0)[i0];
        ((float4*)p.cbuf)[i0 + 16384] = ((const float4*)p.c0)[i0 + 16384];
    }

    // uv (blocks 0-7, 64 cols each, 4-way K-split): rank-1 agent-type folding
    if (b < 8) {
        int lane = t & 63, seg = t >> 6;
        if (t < 64) { float s = 0.f; for (int k = 0; k < 6; ++k) s += p.Wpat[k * 64 + t]; rw2[t] = s; }
        __syncthreads();
        int c = b * 64 + lane;
        float u = 0.f, v = 0.f;
        for (int e = seg * 16; e < seg * 16 + 16; ++e) {
            float wg = p.Wm1[(size_t)(128 + e) * 512 + c];
            u += rw2[e] * wg; v += p.bpat[e] * wg;
        }
        su[seg][lane] = u; sv[seg][lane] = v;
        __syncthreads();
        if (seg == 0) {
            u = su[0][lane] + su[1][lane] + su[2][lane] + su[3][lane];
            v = sv[0][lane] + sv[1][lane] + sv[2][lane] + sv[3][lane];
            p.uv[c] = 0.05f * u; p.uv[512 + c] = 0.05f * v + p.bm1[c];
        }
    }
    // fc (block 8): rank-2 di-fold  F = Wsp@Wih (2x512), C = bsp@Wih + bih + bhh
    if (b == 8) {
        for (int c = t; c < 512; c += 256) {
            float f0 = 0.f, f1 = 0.f, cc = 0.f;
            for (int e = 0; e < 64; ++e) {
                float wv = p.Wih[(size_t)e * 512 + c];
                f0 += p.Wsp[e] * wv; f1 += p.Wsp[64 + e] * wv; cc += p.bsp[e] * wv;
            }
            p.fc[c] = f0; p.fc[512 + c] = f1; p.fc[1024 + c] = cc + p.bih[c] + p.bhh[c];
        }
    }
}

// ---- per step: dh1(prev) -> dh2 -> gates(rank-2 fold + h MFMA) -> LSTM -> rel/m1 ----
// grid 64 x 512 (8 waves); block b: scene s=b>>1, half mt=b&1
__global__ __launch_bounds__(512, 4) void k_step(
    const short* __restrict__ WghHi, const short* __restrict__ WghLo,
    const short* __restrict__ Wm1f, const short* __restrict__ Wd2f,
    const short* __restrict__ Wd1f,
    const float* __restrict__ Whp, const float* __restrict__ bhp,
    const float* __restrict__ bd1, const float* __restrict__ bd2,
    const float* __restrict__ at0, const float* __restrict__ uv,
    const float* __restrict__ fc,
    const float* __restrict__ h0, const float* __restrict__ relsrc,
    const float* __restrict__ phwp, const short* __restrict__ hf_in, int first,
    float* __restrict__ cbuf, short* __restrict__ hf_out,
    short* __restrict__ m1s, float* __restrict__ outrel) {
    __shared__ float sgu[16 * 512];      // 32KB union: dh1L (shorts) / sg (f32)
    __shared__ float sh[16][128];
    __shared__ float phws[1024];
    __shared__ short xfh[4 * 512];
    __shared__ short xfl[4 * 512];
    __shared__ short xm[4 * 512];
    __shared__ float srelp[16][2];
    __shared__ float sat[16];
    short* dh1L = (short*)sgu;
    float* sg = sgu;

    int t = threadIdx.x, b = blockIdx.x;
    int l = t & 63, w = t >> 6;
    int s = b >> 1, mt = b & 1, r0 = b * 16;
    int rbase = (l >> 4) << 2;

    if (t < 16) sat[t] = at0[r0 + t];
    if (t < 32) { int row = t >> 1, d = t & 1; srelp[row][d] = relsrc[(r0 + row) * 2 + d]; }

    if (first) {
        for (int i = t; i < 16 * 128; i += 512) sh[i >> 7][i & 127] = h0[r0 * 128 + i];
        __syncthreads();
    } else {
        // phws = bd1 + sum of 8 phw partials
        for (int i = t; i < 1024; i += 512) {
            float v = bd1[i];
#pragma unroll
            for (int ct = 0; ct < 8; ++ct) v += phwp[(size_t)s * 8192 + ct * 1024 + i];
            phws[i] = v;
        }
        __syncthreads();
        // dh1(prev) = bnrelu(h_prev@Wd1h + phws) -> dh1L A-frags (h-part MFMA, 4 kc)
        short8v Ah[4];
#pragma unroll
        for (int kc = 0; kc < 4; ++kc)
            Ah[kc] = *(const short8v*)(hf_in + (size_t)b * 2048 + kc * 512 + l * 8);
#pragma unroll 1
        for (int q2 = 0; q2 < 4; ++q2) {
            short8v B[2][4];
#pragma unroll
            for (int qq = 0; qq < 2; ++qq)
#pragma unroll
                for (int kc = 0; kc < 4; ++kc)
                    B[qq][kc] = *(const short8v*)(Wd1f + (size_t)(w * 8 + q2 * 2 + qq) * 18432 + kc * 512 + l * 8);
            float4v acc2[2];
#pragma unroll
            for (int qq = 0; qq < 2; ++qq) {
                int col = (w * 8 + q2 * 2 + qq) * 16 + (l & 15);
                float pv = phws[col];
                acc2[qq] = (float4v){pv, pv, pv, pv};
            }
#pragma unroll
            for (int kc = 0; kc < 4; ++kc)
#pragma unroll
                for (int qq = 0; qq < 2; ++qq)
                    acc2[qq] = __builtin_amdgcn_mfma_f32_16x16x32_bf16(Ah[kc], B[qq][kc], acc2[qq], 0, 0, 0);
#pragma unroll
            for (int qq = 0; qq < 2; ++qq) {
                int col = (w * 8 + q2 * 2 + qq) * 16 + (l & 15);
                int kcD = col >> 5, jD = col & 7, lD = ((col & 31) >> 3) << 4;
#pragma unroll
                for (int r = 0; r < 4; ++r) {
                    float v = fmaxf(BN_SF * acc2[qq][r], 0.f);
                    dh1L[kcD * 512 + (rbase + r + lD) * 8 + jD] = f2bf(v);
                }
            }
        }
        __syncthreads();
        // dh2 (K=1024) batched -> h_in
        float4v hacc = {0.f, 0.f, 0.f, 0.f};
        const short* ap = dh1L + l * 8;
        const short* bp = Wd2f + (size_t)w * 16384 + l * 8;
#pragma unroll 1
        for (int kt = 0; kt < 4; ++kt) {
            short8v B[8], A[8];
#pragma unroll
            for (int kk = 0; kk < 8; ++kk) B[kk] = *(const short8v*)(bp + (kt * 8 + kk) * 512);
#pragma unroll
            for (int kk = 0; kk < 8; ++kk) A[kk] = *(const short8v*)(ap + (kt * 8 + kk) * 512);
#pragma unroll
            for (int kk = 0; kk < 8; ++kk)
                hacc = __builtin_amdgcn_mfma_f32_16x16x32_bf16(A[kk], B[kk], hacc, 0, 0, 0);
        }
        int col = w * 16 + (l & 15);
        float bb2 = bd2[col];
        __syncthreads();
#pragma unroll
        for (int r = 0; r < 4; ++r)
            sh[rbase + r][col] = fmaxf(BN_SF * (hacc[r] + bb2), 0.f);
        __syncthreads();
    }

    // xf: h hi/lo A-frags (4 kc)
    for (int i = t; i < 4 * 512; i += 512) {
        int pos = i & 511, kc = i >> 9;
        int ll = pos >> 3, j = pos & 7;
        int row = ll & 15, kh = kc * 32 + ((ll >> 4) << 3) + j;
        float v = sh[row][kh];
        short hi = f2bf(v);
        xfh[i] = hi;
        xfl[i] = f2bf(v - bf2f(hi));
    }
    __syncthreads();

    // gates: rank-2 di-fold init + h-part hi/lo MFMA (4 kc)
    {
        float4v ga[4];
#pragma unroll
        for (int q = 0; q < 4; ++q) {
            int col = (w * 4 + q) * 16 + (l & 15);
            float f0 = fc[col], f1 = fc[512 + col], cc = fc[1024 + col];
#pragma unroll
            for (int r = 0; r < 4; ++r)
                ga[q][r] = srelp[rbase + r][0] * f0 + srelp[rbase + r][1] * f1 + cc;
        }
#pragma unroll 1
        for (int kt = 0; kt < 2; ++kt) {
            short8v BH[2][4], BL[2][4], AH[2], AL[2];
#pragma unroll
            for (int kk = 0; kk < 2; ++kk) {
                int kcx = kt * 2 + kk;
#pragma unroll
                for (int q = 0; q < 4; ++q) {
                    int nf = w * 4 + q;
                    BH[kk][q] = *(const short8v*)(WghHi + (size_t)nf * 2048 + kcx * 512 + l * 8);
                    BL[kk][q] = *(const short8v*)(WghLo + (size_t)nf * 2048 + kcx * 512 + l * 8);
                }
                AH[kk] = *(const short8v*)(&xfh[kcx * 512 + l * 8]);
                AL[kk] = *(const short8v*)(&xfl[kcx * 512 + l * 8]);
            }
#pragma unroll
            for (int kk = 0; kk < 2; ++kk)
#pragma unroll
                for (int q = 0; q < 4; ++q) {
                    ga[q] = __builtin_amdgcn_mfma_f32_16x16x32_bf16(AH[kk], BH[kk][q], ga[q], 0, 0, 0);
                    ga[q] = __builtin_amdgcn_mfma_f32_16x16x32_bf16(AH[kk], BL[kk][q], ga[q], 0, 0, 0);
                    ga[q] = __builtin_amdgcn_mfma_f32_16x16x32_bf16(AL[kk], BH[kk][q], ga[q], 0, 0, 0);
                }
        }
#pragma unroll
        for (int q = 0; q < 4; ++q) {
            int col = (w * 4 + q) * 16 + (l & 15);
#pragma unroll
            for (int r = 0; r < 4; ++r)
                sg[(rbase + r) * 512 + col] = ga[q][r];
        }
    }
    __syncthreads();

    // LSTM pointwise -> sh (new h)
    for (int i = t; i < 16 * 128; i += 512) {
        int row = i >> 7, j = i & 127;
        float gi = sg[row * 512 + j], gf = sg[row * 512 + j + 128];
        float gg = sg[row * 512 + j + 256], go = sg[row * 512 + j + 384];
        float cn = sigm(gf) * cbuf[(r0 + row) * 128 + j] + sigm(gi) * tanhf(gg);
        float hn = sigm(go) * tanhf(cn);
        cbuf[(r0 + row) * 128 + j] = cn;
        sh[row][j] = hn;
    }
    __syncthreads();

    // rel (wave-parallel f32, exact -> out; next step reads it back as relsrc)
    if (t < 256) {
        int row = t >> 4, d = (t >> 3) & 1, seg = t & 7;
        float v = 0.f;
#pragma unroll
        for (int kk = 0; kk < 16; ++kk) {
            int k = seg * 16 + kk;
            v += sh[row][k] * Whp[k * 2 + d];
        }
        v += __shfl_xor(v, 1, 64); v += __shfl_xor(v, 2, 64); v += __shfl_xor(v, 4, 64);
        if (seg == 0) outrel[(r0 + row) * 2 + d] = v + bhp[d];
    }
    // new-h A-frags (LDS xm + global hf)
    for (int i = t; i < 4 * 512; i += 512) {
        int pos = i & 511, kc = i >> 9;
        int ll = pos >> 3, j = pos & 7;
        int row = ll & 15, k = kc * 32 + ((ll >> 4) << 3) + j;
        short hv = f2bf(sh[row][k]);
        xm[i] = hv;
        hf_out[(size_t)b * 2048 + i] = hv;
    }
    __syncthreads();

    // m1 MFMA -> m1s
    {
        float4v ma[4] = {{0,0,0,0},{0,0,0,0},{0,0,0,0},{0,0,0,0}};
        short8v A[4], B[4][4];
#pragma unroll
        for (int kc = 0; kc < 4; ++kc) {
#pragma unroll
            for (int q = 0; q < 4; ++q)
                B[kc][q] = *(const short8v*)(Wm1f + (size_t)(w * 4 + q) * 2048 + kc * 512 + l * 8);
            A[kc] = *(const short8v*)(&xm[kc * 512 + l * 8]);
        }
#pragma unroll
        for (int kc = 0; kc < 4; ++kc)
#pragma unroll
            for (int q = 0; q < 4; ++q)
                ma[q] = __builtin_amdgcn_mfma_f32_16x16x32_bf16(A[kc], B[kc][q], ma[q], 0, 0, 0);
#pragma unroll
        for (int q = 0; q < 4; ++q) {
            int col = (w * 4 + q) * 16 + (l & 15);
            float uc = uv[col], vc = uv[512 + col];
#pragma unroll
            for (int r = 0; r < 4; ++r) {
                int rowC = rbase + r;
                float m1v = fmaxf(BN_SF * (ma[q][r] + sat[rowC] * uc + vc), 0.f);
                int kcD = col >> 5;
                int laneD = rowC + (((col & 31) >> 3) << 4);
                m1s[(size_t)s * 16384 + kcD * 1024 + mt * 512 + laneD * 8 + (col & 7)] = f2bf(m1v);
            }
        }
    }
}

// ---- per step: m2 (MFMA) + colmax -> ph slice -> partial phw (K-split) ----
// grid 256 = 32 scenes x 8 K/col-slices; 512 thr = 8 waves
__global__ __launch_bounds__(512, 4) void k_m2(const short* __restrict__ m1s,
                                               const short* __restrict__ Wm2s,
                                               const short* __restrict__ Wd1f,
                                               const float* __restrict__ bm2,
                                               float* __restrict__ phwp) {
    __shared__ short sphb[128];
    int t = threadIdx.x, l = t & 63, w = t >> 6;
    int s = blockIdx.x >> 3, ct = blockIdx.x & 7;

    // m2: wave w -> nf = ct*8+w, both m-halves
    {
        int nf = ct * 8 + w;
        const short* ap = m1s + (size_t)s * 16384 + l * 8;
        const short* bp = Wm2s + (size_t)nf * 8192 + l * 8;
        float4v acc0 = {0,0,0,0}, acc1 = {0,0,0,0};
#pragma unroll 1
        for (int kt = 0; kt < 4; ++kt) {
            short8v A0[4], A1[4], B[4];
#pragma unroll
            for (int kk = 0; kk < 4; ++kk) {
                int kc = kt * 4 + kk;
                B[kk] = *(const short8v*)(bp + kc * 512);
                A0[kk] = *(const short8v*)(ap + kc * 1024);
                A1[kk] = *(const short8v*)(ap + kc * 1024 + 512);
            }
#pragma unroll
            for (int kk = 0; kk < 4; ++kk) {
                acc0 = __builtin_amdgcn_mfma_f32_16x16x32_bf16(A0[kk], B[kk], acc0, 0, 0, 0);
                acc1 = __builtin_amdgcn_mfma_f32_16x16x32_bf16(A1[kk], B[kk], acc1, 0, 0, 0);
            }
        }
        float m = acc0[0];
#pragma unroll
        for (int ri = 1; ri < 4; ++ri) m = fmaxf(m, acc0[ri]);
#pragma unroll
        for (int ri = 0; ri < 4; ++ri) m = fmaxf(m, acc1[ri]);
        m = fmaxf(m, __shfl_xor(m, 16, 64));
        m = fmaxf(m, __shfl_xor(m, 32, 64));
        if (l < 16) {
            int col = nf * 16 + l;
            sphb[w * 16 + l] = f2bf(fmaxf(BN_SF * (m + bm2[col]), 0.f));
        }
    }
    __syncthreads();

    // phw partial: ph-slice(128) @ Wd1p[4+ct*4 kc, all 1024 cols], broadcast-A
    {
        short8v Ap[4];
#pragma unroll
        for (int kk = 0; kk < 4; ++kk)
            Ap[kk] = *(const short8v*)(sphb + kk * 32 + ((l >> 4) << 3));
#pragma unroll 1
        for (int q2 = 0; q2 < 4; ++q2) {
            short8v B[2][4];
#pragma unroll
            for (int qq = 0; qq < 2; ++qq)
#pragma unroll
                for (int kk = 0; kk < 4; ++kk)
                    B[qq][kk] = *(const short8v*)(Wd1f + (size_t)(w * 8 + q2 * 2 + qq) * 18432
                                                  + (size_t)(4 + ct * 4 + kk) * 512 + l * 8);
            float4v acc2[2] = {{0,0,0,0},{0,0,0,0}};
#pragma unroll
            for (int kk = 0; kk < 4; ++kk)
#pragma unroll
                for (int qq = 0; qq < 2; ++qq)
                    acc2[qq] = __builtin_amdgcn_mfma_f32_16x16x32_bf16(Ap[kk], B[qq][kk], acc2[qq], 0, 0, 0);
            if (l < 16) {
#pragma unroll
                for (int qq = 0; qq < 2; ++qq) {
                    int nf_p = w * 8 + q2 * 2 + qq;
                    phwp[(size_t)s * 8192 + ct * 1024 + nf_p * 16 + l] = acc2[qq][0];
                }
            }
        }
    }
}

// ---- final: dh1(11) from hf+phwp, dh2 -> out h ----
__global__ __launch_bounds__(512, 4) void k_hfin(const short* __restrict__ Wd2f,
                                                 const short* __restrict__ Wd1f,
                                                 const float* __restrict__ bd1,
                                                 const float* __restrict__ bd2,
                                                 const float* __restrict__ phwp,
                                                 const short* __restrict__ hf,
                                                 float* __restrict__ outh) {
    __shared__ float phws[1024];
    __shared__ short dh1L[16384];
    int t = threadIdx.x, b = blockIdx.x;
    int l = t & 63, w = t >> 6;
    int s = b >> 1, rbase = (l >> 4) << 2;

    for (int i = t; i < 1024; i += 512) {
        float v = bd1[i];
#pragma unroll
        for (int ct = 0; ct < 8; ++ct) v += phwp[(size_t)s * 8192 + ct * 1024 + i];
        phws[i] = v;
    }
    __syncthreads();
    short8v Ah[4];
#pragma unroll
    for (int kc = 0; kc < 4; ++kc)
        Ah[kc] = *(const short8v*)(hf + (size_t)b * 2048 + kc * 512 + l * 8);
#pragma unroll 1
    for (int q2 = 0; q2 < 4; ++q2) {
        short8v B[2][4];
#pragma unroll
        for (int qq = 0; qq < 2; ++qq)
#pragma unroll
            for (int kc = 0; kc < 4; ++kc)
                B[qq][kc] = *(const short8v*)(Wd1f + (size_t)(w * 8 + q2 * 2 + qq) * 18432 + kc * 512 + l * 8);
        float4v acc2[2];
#pragma unroll
        for (int qq = 0; qq < 2; ++qq) {
            int col = (w * 8 + q2 * 2 + qq) * 16 + (l & 15);
            float pv = phws[col];
            acc2[qq] = (float4v){pv, pv, pv, pv};
        }
#pragma unroll
        for (int kc = 0; kc < 4; ++kc)
#pragma unroll
            for (int qq = 0; qq < 2; ++qq)
                acc2[qq] = __builtin_amdgcn_mfma_f32_16x16x32_bf16(Ah[kc], B[qq][kc], acc2[qq], 0, 0, 0);
#pragma unroll
        for (int qq = 0; qq < 2; ++qq) {
            int col = (w * 8 + q2 * 2 + qq) * 16 + (l & 15);
            int kcD = col >> 5, jD = col & 7, lD = ((col & 31) >> 3) << 4;
#pragma unroll
            for (int r = 0; r < 4; ++r) {
                float v = fmaxf(BN_SF * acc2[qq][r], 0.f);
                dh1L[kcD * 512 + (rbase + r + lD) * 8 + jD] = f2bf(v);
            }
        }
    }
    __syncthreads();
    float4v hacc = {0.f, 0.f, 0.f, 0.f};
    const short* ap = dh1L + l * 8;
    const short* bp = Wd2f + (size_t)w * 16384 + l * 8;
#pragma unroll 1
    for (int kt = 0; kt < 4; ++kt) {
        short8v B[8], A[8];
#pragma unroll
        for (int kk = 0; kk < 8; ++kk) B[kk] = *(const short8v*)(bp + (kt * 8 + kk) * 512);
#pragma unroll
        for (int kk = 0; kk < 8; ++kk) A[kk] = *(const short8v*)(ap + (kt * 8 + kk) * 512);
#pragma unroll
        for (int kk = 0; kk < 8; ++kk)
            hacc = __builtin_amdgcn_mfma_f32_16x16x32_bf16(A[kk], B[kk], hacc, 0, 0, 0);
    }
    int col = w * 16 + (l & 15);
    float bb2 = bd2[col];
#pragma unroll
    for (int r = 0; r < 4; ++r)
        outh[(b * 16 + rbase + r) * 128 + col] = fmaxf(BN_SF * (hacc[r] + bb2), 0.f);
}

extern "C" void kernel_launch(void* const* d_in, const int* in_sizes, int n_in,
                              void* d_out, int out_size, void* d_ws, size_t ws_size,
                              hipStream_t stream) {
    const float* lpr   = (const float*)d_in[1];
    const float* h0    = (const float*)d_in[2];
    const float* c0    = (const float*)d_in[3];
    const float* at0   = (const float*)d_in[6];
    const float* W_sp  = (const float*)d_in[8];
    const float* b_sp  = (const float*)d_in[9];
    const float* W_ih  = (const float*)d_in[10];
    const float* W_hh  = (const float*)d_in[11];
    const float* b_ih  = (const float*)d_in[12];
    const float* b_hh  = (const float*)d_in[13];
    const float* W_h2p = (const float*)d_in[14];
    const float* b_h2p = (const float*)d_in[15];
    const float* Wp_at = (const float*)d_in[20];
    const float* bp_at = (const float*)d_in[21];
    const float* Wm1   = (const float*)d_in[26];
    const float* bm1   = (const float*)d_in[27];
    const float* Wm2   = (const float*)d_in[28];
    const float* bm2   = (const float*)d_in[29];
    const float* Wd1   = (const float*)d_in[30];
    const float* bd1   = (const float*)d_in[31];
    const float* Wd2   = (const float*)d_in[32];
    const float* bd2   = (const float*)d_in[33];
    float* out = (float*)d_out;

    float* ws    = (float*)d_ws;
    float* uv    = ws;                       // 1024 f
    float* fc    = uv + 1024;                // 1536 f
    float* cbuf  = fc + 1536;                // 131072 f
    float* phwp  = cbuf + 131072;            // 262144 f
    short* hf    = (short*)(phwp + 262144);  // 131072 sh
    short* m1s   = hf + 131072;              // 524288 sh
    short* Wm2s  = m1s + 524288;             // 524288 sh
    short* Wd1f  = Wm2s + 524288;            // 1179648 sh
    short* Wd2f  = Wd1f + 1179648;           // 131072 sh
    short* Wm1f  = Wd2f + 131072;            // 65536 sh
    short* WghHi = Wm1f + 65536;             // 65536 sh
    short* WghLo = WghHi + 65536;            // 65536 sh

    SetupP sp;
    sp.Wm2 = Wm2; sp.Wd1 = Wd1; sp.Wd2 = Wd2; sp.Wm1 = Wm1;
    sp.Wih = W_ih; sp.Whh = W_hh; sp.Wpat = Wp_at; sp.bpat = bp_at; sp.bm1 = bm1;
    sp.c0 = c0; sp.Wsp = W_sp; sp.bsp = b_sp; sp.bih = b_ih; sp.bhh = b_hh;
    sp.Wm2s = Wm2s; sp.Wd1f = Wd1f; sp.Wd2f = Wd2f;
    sp.Wm1f = Wm1f; sp.WghHi = WghHi; sp.WghLo = WghLo;
    sp.uv = uv; sp.cbuf = cbuf; sp.fc = fc;

    k_setup<<<1024, 256, 0, stream>>>(sp);

    for (int t = 0; t < 12; ++t) {
        const float* relsrc = (t == 0) ? lpr : (out + (size_t)(t - 1) * 2048);
        k_step<<<64, 512, 0, stream>>>(WghHi, WghLo, Wm1f, Wd2f, Wd1f,
                                       W_h2p, b_h2p, bd1, bd2, at0, uv, fc,
                                       h0, relsrc, phwp, hf, (t == 0) ? 1 : 0,
                                       cbuf, hf, m1s, out + (size_t)t * 2048);
        k_m2<<<256, 512, 0, stream>>>(m1s, Wm2s, Wd1f, bm2, phwp);
    }
    k_hfin<<<64, 512, 0, stream>>>(Wd2f, Wd1f, bd1, bd2, phwp, hf, out + 24576);
}